// Round 4
// baseline (880.670 us; speedup 1.0000x reference)
//
#include <hip/hip_runtime.h>

// Problem constants
#define Bv    32
#define Lv    512
#define Hv    512
#define Fv    512
#define Tv    4096
#define Mv    (Bv*Lv)          // 16384 rows
#define NBINSv 256

// d_out layout (floats): out(B,T,H) | pit(B,L) | eng(B,L) | log_dur(B,L) | mel_len(B)
#define OUT_OFF 0
#define PIT_OFF (Bv*(size_t)Tv*Hv)              // 67108864
#define ENG_OFF (PIT_OFF + Mv)
#define DUR_OFF (ENG_OFF + Mv)
#define MEL_OFF (DUR_OFF + Mv)

typedef unsigned short ushort;
typedef __attribute__((ext_vector_type(8))) short   bf16x8;   // 8 bf16 in 4 VGPRs
typedef __attribute__((ext_vector_type(4))) float   f32x4;
typedef __attribute__((ext_vector_type(8))) unsigned short u16x8;

__device__ __forceinline__ float b2f(ushort u) {
    union { float f; unsigned u; } x; x.u = ((unsigned)u) << 16; return x.f;
}
__device__ __forceinline__ ushort f2b(float f) {
    union { float f; unsigned u; } x; x.f = f;
    unsigned r = x.u + 0x7fffu + ((x.u >> 16) & 1u);   // RNE
    return (ushort)(r >> 16);
}

#define GLL16(g, l) __builtin_amdgcn_global_load_lds( \
    (const __attribute__((address_space(1))) void*)(g), \
    (__attribute__((address_space(3))) void*)(l), 16, 0, 0)

// Struct-of-pointers kernel args for z-batched launches
template<int NZ> struct GArgs {
    const ushort* A[NZ];
    const ushort* W[NZ];
    const float*  bias[NZ];
    ushort*       C[NZ];
};
struct RmsArgs   { const ushort* h[3]; const float* g[3]; ushort* o[3]; };
struct RlArgs    { const ushort* h[3]; const float* g[3]; const float* wl[3]; const float* bl[3]; };
struct TransArgs { const float* src[6]; ushort* dst[6]; };
struct ConvArgs  { const float* src[2]; ushort* dst[2]; };

// ---------------------------------------------------------------------------
// bf16 MFMA GEMM, z-batched.  C[m,n] = epi( sum A*Wt + bias )
// Tile 128x128, BK=32, 256 thr = 4 waves, 4x4 16x16x32 MFMA tiles / wave.
// Operand-swapped MFMA: acc[j][i] = mfma(Wfrag[j], Afrag[i], acc) so D has
// m on col=lane&15 and n on row=q*4+reg -> lane holds 4 CONSECUTIVE n values
// -> vectorized (8B stores / float4 loads) epilogue.
// NTAPS=3 folds K=3 conv taps (zero pad via zero-page redirect), tap-outer.
// EPI: 0 relu; 1 relu+res; 2 relu+res+pe[idxp]+ee[idxe]
// ---------------------------------------------------------------------------
template<int NTAPS, int EPI, int NZ>
__global__ __launch_bounds__(256) void gemm_bf16_kernel(
    GArgs<NZ> ga, const float* __restrict__ res, const float* __restrict__ pe,
    const float* __restrict__ ee, const int* __restrict__ idxp,
    const int* __restrict__ idxe, const ushort* __restrict__ zp)
{
    constexpr int KTOT = NTAPS * 512;
    const int z = (NZ > 1) ? blockIdx.z : 0;
    const ushort* __restrict__ A    = ga.A[z];
    const ushort* __restrict__ Bt   = ga.W[z];
    const float*  __restrict__ bias = ga.bias[z];
    ushort*       __restrict__ C    = ga.C[z];

    __shared__ ushort As[128 * 32];
    __shared__ ushort Bs[128 * 32];

    const int tid = threadIdx.x;
    const int n0 = blockIdx.x * 128;
    const int m0 = blockIdx.y * 128;

    // staging: wave-contiguous so GLL16's base+lane*16 layout matches row-major
    const int sar = tid >> 2;       // row 0..63 (plus +64 for second half)
    const int sl  = tid & 3;        // 16B slot = k-chunk (no swizzle)

    const int lane = tid & 63;
    const int w    = tid >> 6;
    const int wm   = (w & 1) * 64;
    const int wn   = (w >> 1) * 64;
    const int lr   = lane & 15;
    const int q    = lane >> 4;

    // LDS destinations (loop-invariant)
    ushort* asd0 = &As[sar * 32 + sl * 8];
    ushort* asd1 = &As[(sar + 64) * 32 + sl * 8];
    ushort* bsd0 = &Bs[sar * 32 + sl * 8];
    ushort* bsd1 = &Bs[(sar + 64) * 32 + sl * 8];

    f32x4 acc[4][4];   // acc[j][i]: j = n-tile, i = m-tile
    #pragma unroll
    for (int j = 0; j < 4; ++j)
        #pragma unroll
        for (int i = 0; i < 4; ++i) {
            f32x4 zz = {0.f, 0.f, 0.f, 0.f};
            acc[j][i] = zz;
        }

    for (int tap = 0; tap < NTAPS; ++tap) {
        // hoisted per-tap staging bases (nullptr = zero-pad row)
        const ushort* ab[2];
        #pragma unroll
        for (int r = 0; r < 2; ++r) {
            const int row = sar + r * 64;
            const int m   = m0 + row;
            if (NTAPS == 3) {
                const int l  = m & (Lv - 1);
                const int ls = l + tap - 1;
                ab[r] = ((unsigned)ls < (unsigned)Lv)
                      ? A + (size_t)(m + tap - 1) * 512 + sl * 8 : nullptr;
            } else {
                ab[r] = A + (size_t)m * 512 + sl * 8;
            }
        }
        const ushort* bb0 = Bt + (size_t)(n0 + sar) * KTOT + tap * 512 + sl * 8;
        const ushort* bb1 = Bt + (size_t)(n0 + sar + 64) * KTOT + tap * 512 + sl * 8;

        for (int kt = 0; kt < 16; ++kt) {
            const int kin = kt << 5;
            GLL16(ab[0] ? ab[0] + kin : zp, asd0);
            GLL16(bb0 + kin, bsd0);
            GLL16(ab[1] ? ab[1] + kin : zp, asd1);
            GLL16(bb1 + kin, bsd1);
            __syncthreads();

            bf16x8 af[4], bfr[4];
            #pragma unroll
            for (int i = 0; i < 4; ++i) {
                af[i]  = *(const bf16x8*)&As[(wm + i * 16 + lr) * 32 + q * 8];
                bfr[i] = *(const bf16x8*)&Bs[(wn + i * 16 + lr) * 32 + q * 8];
            }
            #pragma unroll
            for (int j = 0; j < 4; ++j)
                #pragma unroll
                for (int i = 0; i < 4; ++i)
                    acc[j][i] = __builtin_amdgcn_mfma_f32_16x16x32_bf16(
                                    bfr[j], af[i], acc[j][i], 0, 0, 0);
            __syncthreads();
        }
    }

    // Vectorized epilogue: lane owns m = wm+i*16+lr, n = wn+j*16+q*4 .. +3
    #pragma unroll
    for (int i = 0; i < 4; ++i) {
        const int m = m0 + wm + i * 16 + lr;
        const size_t ro = (size_t)m * 512;
        int ip = 0, ie = 0;
        if (EPI == 2) { ip = idxp[m]; ie = idxe[m]; }
        #pragma unroll
        for (int j = 0; j < 4; ++j) {
            const int n = n0 + wn + j * 16 + q * 4;
            const f32x4 a = acc[j][i];
            const float4 bi = *(const float4*)(bias + n);
            float v0 = fmaxf(a[0] + bi.x, 0.f);
            float v1 = fmaxf(a[1] + bi.y, 0.f);
            float v2 = fmaxf(a[2] + bi.z, 0.f);
            float v3 = fmaxf(a[3] + bi.w, 0.f);
            if (EPI >= 1) {
                const float4 r4 = *(const float4*)(res + ro + n);
                v0 += r4.x; v1 += r4.y; v2 += r4.z; v3 += r4.w;
            }
            if (EPI == 2) {
                const float4 p4 = *(const float4*)(pe + (size_t)ip * 512 + n);
                const float4 e4 = *(const float4*)(ee + (size_t)ie * 512 + n);
                v0 += p4.x + e4.x; v1 += p4.y + e4.y;
                v2 += p4.z + e4.z; v3 += p4.w + e4.w;
            }
            ushort4 o4;
            o4.x = f2b(v0); o4.y = f2b(v1); o4.z = f2b(v2); o4.w = f2b(v3);
            *(ushort4*)(C + ro + n) = o4;
        }
    }
}

// ---------------------------------------------------------------------------
// fp32 -> bf16 convert, batched over {x, emb}
// ---------------------------------------------------------------------------
__global__ __launch_bounds__(256) void convert_kernel(ConvArgs ca)
{
    const float* __restrict__ X  = ca.src[blockIdx.y];
    ushort*      __restrict__ Xb = ca.dst[blockIdx.y];
    const size_t i = (size_t)blockIdx.x * 256 + threadIdx.x;
    const float4 a = ((const float4*)X)[2 * i];
    const float4 b = ((const float4*)X)[2 * i + 1];
    u16x8 o;
    o[0] = f2b(a.x); o[1] = f2b(a.y); o[2] = f2b(a.z); o[3] = f2b(a.w);
    o[4] = f2b(b.x); o[5] = f2b(b.y); o[6] = f2b(b.z); o[7] = f2b(b.w);
    *(u16x8*)(Xb + i * 8) = o;
}

// ---------------------------------------------------------------------------
// Weight transpose+convert, z-batched: W[kk][n] fp32 -> Wt[n][kk] bf16
// ---------------------------------------------------------------------------
__global__ __launch_bounds__(256) void transpose_kernel(TransArgs ta, int Ktot)
{
    const float* __restrict__ W  = ta.src[blockIdx.z];
    ushort*      __restrict__ Wt = ta.dst[blockIdx.z];
    __shared__ float t[32][33];
    const int k0 = blockIdx.x * 32, n0 = blockIdx.y * 32;
    const int r = threadIdx.x >> 5, c = threadIdx.x & 31;
    #pragma unroll
    for (int rr = 0; rr < 4; ++rr)
        t[r + rr * 8][c] = W[(size_t)(k0 + r + rr * 8) * 512 + n0 + c];
    __syncthreads();
    #pragma unroll
    for (int rr = 0; rr < 4; ++rr)
        Wt[(size_t)(n0 + r + rr * 8) * Ktot + k0 + c] = f2b(t[c][r + rr * 8]);
}

// ---------------------------------------------------------------------------
// RMSNorm, z-batched. bf16 in/out, fp32 math.
// ---------------------------------------------------------------------------
__global__ __launch_bounds__(128) void rms_kernel(RmsArgs ra)
{
    const int z = blockIdx.y;
    const int row = blockIdx.x;
    const int tid = threadIdx.x;
    const ushort* __restrict__ h = ra.h[z];
    const ushort4 hv = ((const ushort4*)(h + (size_t)row * 512))[tid];
    const float v0 = b2f(hv.x), v1 = b2f(hv.y), v2 = b2f(hv.z), v3 = b2f(hv.w);
    float ss = v0 * v0 + v1 * v1 + v2 * v2 + v3 * v3;
    #pragma unroll
    for (int off = 32; off; off >>= 1) ss += __shfl_down(ss, off, 64);
    __shared__ float p[2];
    if ((tid & 63) == 0) p[tid >> 6] = ss;
    __syncthreads();
    const float tot = p[0] + p[1];
    const float inv = 1.f / (sqrtf(tot * (1.f / 512.f)) + 1e-8f);
    const float4 gv = ((const float4*)ra.g[z])[tid];
    ushort4 ov;
    ov.x = f2b(gv.x * v0 * inv); ov.y = f2b(gv.y * v1 * inv);
    ov.z = f2b(gv.z * v2 * inv); ov.w = f2b(gv.w * v3 * inv);
    ((ushort4*)(ra.o[z] + (size_t)row * 512))[tid] = ov;
}

// ---------------------------------------------------------------------------
// Fused RMSNorm + linear head, z-batched. pred = mask ? 0 : inv*sum(g*h*wl)+bl
// ---------------------------------------------------------------------------
__global__ __launch_bounds__(256) void rmslin_kernel(
    RlArgs ra, const unsigned char* __restrict__ mask, float* __restrict__ predbase)
{
    const int z = blockIdx.y;
    const int wave = threadIdx.x >> 6, lane = threadIdx.x & 63;
    const int row = blockIdx.x * 4 + wave;
    const ushort* __restrict__ h = ra.h[z];
    const bf16x8 hv = *(const bf16x8*)(h + (size_t)row * 512 + lane * 8);
    const float4 g0 = *(const float4*)(ra.g[z] + lane * 8);
    const float4 g1 = *(const float4*)(ra.g[z] + lane * 8 + 4);
    const float4 w0 = *(const float4*)(ra.wl[z] + lane * 8);
    const float4 w1 = *(const float4*)(ra.wl[z] + lane * 8 + 4);
    float hf[8];
    #pragma unroll
    for (int t = 0; t < 8; ++t) hf[t] = b2f((ushort)hv[t]);
    float ss = 0.f, sgw = 0.f;
    #pragma unroll
    for (int t = 0; t < 8; ++t) ss += hf[t] * hf[t];
    sgw += hf[0]*g0.x*w0.x + hf[1]*g0.y*w0.y + hf[2]*g0.z*w0.z + hf[3]*g0.w*w0.w;
    sgw += hf[4]*g1.x*w1.x + hf[5]*g1.y*w1.y + hf[6]*g1.z*w1.z + hf[7]*g1.w*w1.w;
    #pragma unroll
    for (int off = 32; off; off >>= 1) {
        ss  += __shfl_down(ss,  off, 64);
        sgw += __shfl_down(sgw, off, 64);
    }
    if (lane == 0) {
        const float inv = 1.f / (sqrtf(ss * (1.f / 512.f)) + 1e-8f);
        predbase[(size_t)z * Mv + row] = mask[row] ? 0.f : (sgw * inv + ra.bl[z][0]);
    }
}

// ---------------------------------------------------------------------------
// searchsorted(bins, v, 'left') for pitch & energy targets
// ---------------------------------------------------------------------------
__global__ __launch_bounds__(256) void idx_kernel(
    const float* __restrict__ pt, const float* __restrict__ et,
    const float* __restrict__ pbins, const float* __restrict__ ebins,
    int* __restrict__ idxp, int* __restrict__ idxe)
{
    __shared__ float pb[NBINSv - 1], ebn[NBINSv - 1];
    const int tid = threadIdx.x;
    if (tid < NBINSv - 1) { pb[tid] = pbins[tid]; ebn[tid] = ebins[tid]; }
    __syncthreads();
    const int m = blockIdx.x * 256 + tid;
    const float pv = pt[m], ev = et[m];
    int lo = 0, hi = NBINSv - 1;
    while (lo < hi) { int mid = (lo + hi) >> 1; if (pb[mid] < pv) lo = mid + 1; else hi = mid; }
    idxp[m] = lo;
    lo = 0; hi = NBINSv - 1;
    while (lo < hi) { int mid = (lo + hi) >> 1; if (ebn[mid] < ev) lo = mid + 1; else hi = mid; }
    idxe[m] = lo;
}

// ---------------------------------------------------------------------------
// Fused cumsum + mel_len + regulate source map.
// One block (512 thr) per batch: scan durations in LDS, then each thread
// binary-searches 8 t positions against the LDS cum array.
// ---------------------------------------------------------------------------
__global__ __launch_bounds__(512) void cumtmap_kernel(
    const int* __restrict__ dur, float* __restrict__ melout, int* __restrict__ tmap)
{
    __shared__ int s[Lv];
    const int b = blockIdx.x, tid = threadIdx.x;
    s[tid] = dur[b * Lv + tid];
    __syncthreads();
    for (int off = 1; off < Lv; off <<= 1) {
        int t = (tid >= off) ? s[tid - off] : 0;
        __syncthreads();
        s[tid] += t;
        __syncthreads();
    }
    const int mel = s[Lv - 1];
    if (tid == 0) melout[b] = (float)mel;
    #pragma unroll
    for (int rr = 0; rr < Tv / 512; ++rr) {
        const int t = tid + rr * 512;
        int lo = 0, hi = Lv;
        while (lo < hi) { int mid = (lo + hi) >> 1; if (s[mid] <= t) lo = mid + 1; else hi = mid; }
        tmap[b * Tv + t] = (t < mel) ? (b * Lv + min(lo, Lv - 1)) : -1;
    }
}

// ---------------------------------------------------------------------------
// Length regulate gather: out[bt,:] = tmap[bt] >= 0 ? xo[tmap[bt],:] : 0
// ---------------------------------------------------------------------------
__global__ __launch_bounds__(128) void regulate_kernel(
    const ushort* __restrict__ xo, const int* __restrict__ tmap,
    float* __restrict__ out)
{
    const int bt = blockIdx.x;
    const int src = tmap[bt];
    float4 v = make_float4(0.f, 0.f, 0.f, 0.f);
    if (src >= 0) {
        const ushort4 u = ((const ushort4*)(xo + (size_t)src * 512))[threadIdx.x];
        v.x = b2f(u.x); v.y = b2f(u.y); v.z = b2f(u.z); v.w = b2f(u.w);
    }
    ((float4*)(out + (size_t)bt * 512))[threadIdx.x] = v;
}

// ---------------------------------------------------------------------------
extern "C" void kernel_launch(void* const* d_in, const int* in_sizes, int n_in,
                              void* d_out, int out_size, void* d_ws, size_t ws_size,
                              hipStream_t stream)
{
    const float* x    = (const float*)d_in[0];
    const float* emb  = (const float*)d_in[1];
    const unsigned char* mask = (const unsigned char*)d_in[2];
    const int*   durt = (const int*)d_in[3];
    const float* pt   = (const float*)d_in[4];
    const float* et   = (const float*)d_in[5];
    const float* dw1 = (const float*)d_in[7],  *db1 = (const float*)d_in[8],
               * dg1 = (const float*)d_in[9],  *dw2 = (const float*)d_in[10],
               * db2 = (const float*)d_in[11], *dg2 = (const float*)d_in[12],
               * dwl = (const float*)d_in[13], *dbl = (const float*)d_in[14];
    const float* pw1 = (const float*)d_in[15], *pb1 = (const float*)d_in[16],
               * pg1 = (const float*)d_in[17], *pw2 = (const float*)d_in[18],
               * pb2 = (const float*)d_in[19], *pg2 = (const float*)d_in[20],
               * pwl = (const float*)d_in[21], *pbl = (const float*)d_in[22];
    const float* ew1 = (const float*)d_in[23], *eb1 = (const float*)d_in[24],
               * eg1 = (const float*)d_in[25], *ew2 = (const float*)d_in[26],
               * eb2 = (const float*)d_in[27], *eg2 = (const float*)d_in[28],
               * ewl = (const float*)d_in[29], *ebl = (const float*)d_in[30];
    const float* ppw1 = (const float*)d_in[31], *ppb1 = (const float*)d_in[32],
               * ppw2 = (const float*)d_in[33], *ppb2 = (const float*)d_in[34];
    const float* epw1 = (const float*)d_in[35], *epb1 = (const float*)d_in[36],
               * epw2 = (const float*)d_in[37], *epb2 = (const float*)d_in[38];
    const float* spw1 = (const float*)d_in[39], *spb1 = (const float*)d_in[40],
               * spw2 = (const float*)d_in[41], *spb2 = (const float*)d_in[42];
    const float* pbins = (const float*)d_in[43];
    const float* ebins = (const float*)d_in[44];
    const float* pemb  = (const float*)d_in[45];
    const float* eemb  = (const float*)d_in[46];

    float* outf = (float*)d_out;

    // ---- ws scratch (int offsets) ----
    int*    idxp   = (int*)d_ws;                    // 16384
    int*    idxe   = idxp + 16384;                  // 16384
    ushort* zp     = (ushort*)(idxe + 16384);       // 32 ushorts (16B-aligned)
    int*    tmap   = idxe + 16448;                  // 131072
    ushort* xob    = (ushort*)((float*)d_ws + 262144);  // Mv*512 bf16, 1MB offset

    // ---- d_out front scratch (float offsets; regulate overwrites all) ----
    #define OBUF(i) ((ushort*)(outf + (size_t)(i) * 4194304))
    ushort* xb  = OBUF(0);   ushort* eb  = OBUF(1);
    ushort* pA0 = OBUF(2);   ushort* pA1 = OBUF(3);  ushort* pA2 = OBUF(4);
    ushort* xp  = OBUF(5);   ushort* xe  = OBUF(6);
    ushort* c0  = OBUF(7);   ushort* c1  = OBUF(8);  ushort* c2  = OBUF(9);
    ushort* r0  = OBUF(10);  ushort* r1  = OBUF(11); ushort* r2  = OBUF(12);
    ushort* wt[12];
    {
        size_t off = 13ull * 4194304;
        for (int i = 0; i < 6; ++i)  { wt[i] = (ushort*)(outf + off); off += 393216; }  // conv 1536x512
        for (int i = 6; i < 12; ++i) { wt[i] = (ushort*)(outf + off); off += 131072; }  // proj 512x512
    }

    hipMemsetAsync(zp, 0, 64, stream);

    { ConvArgs ca = {{x, emb}, {xb, eb}};
      convert_kernel<<<dim3(4096, 2), 256, 0, stream>>>(ca); }
    { TransArgs ta = {{dw1, dw2, pw1, pw2, ew1, ew2}, {wt[0], wt[1], wt[2], wt[3], wt[4], wt[5]}};
      transpose_kernel<<<dim3(48, 16, 6), 256, 0, stream>>>(ta, 1536); }
    { TransArgs ta = {{ppw1, ppw2, epw1, epw2, spw1, spw2},
                      {wt[6], wt[7], wt[8], wt[9], wt[10], wt[11]}};
      transpose_kernel<<<dim3(16, 16, 6), 256, 0, stream>>>(ta, 512); }

    idx_kernel<<<Mv / 256, 256, 0, stream>>>(pt, et, pbins, ebins, idxp, idxe);
    cumtmap_kernel<<<Bv, Lv, 0, stream>>>(durt, outf + MEL_OFF, tmap);

    const dim3 g3(Fv / 128, Mv / 128, 3);
    const dim3 g2(Fv / 128, Mv / 128, 2);
    const dim3 g1(Fv / 128, Mv / 128, 1);

    // proj1: h = relu(emb @ w1 + b1) for pp/ep/sp
    { GArgs<3> a = {{eb, eb, eb}, {wt[6], wt[8], wt[10]}, {ppb1, epb1, spb1}, {pA0, pA1, pA2}};
      gemm_bf16_kernel<1, 0, 3><<<g3, 256, 0, stream>>>(a, nullptr, nullptr, nullptr,
                                                        nullptr, nullptr, zp); }
    // proj2 pp/ep: xin = x + relu(h @ w2 + b2)
    { GArgs<2> a = {{pA0, pA1}, {wt[7], wt[9]}, {ppb2, epb2}, {xp, xe}};
      gemm_bf16_kernel<1, 1, 2><<<g2, 256, 0, stream>>>(a, x, nullptr, nullptr,
                                                        nullptr, nullptr, zp); }
    // proj2 sp: xo = x + pe + ee + relu(h @ w2 + b2)
    { GArgs<1> a = {{pA2}, {wt[11]}, {spb2}, {xob}};
      gemm_bf16_kernel<1, 2, 1><<<g1, 256, 0, stream>>>(a, x, pemb, eemb, idxp, idxe, zp); }

    // conv1 for {pit, eng, dur}
    { GArgs<3> a = {{xp, xe, xb}, {wt[2], wt[4], wt[0]}, {pb1, eb1, db1}, {c0, c1, c2}};
      gemm_bf16_kernel<3, 0, 3><<<g3, 256, 0, stream>>>(a, nullptr, nullptr, nullptr,
                                                        nullptr, nullptr, zp); }
    { RmsArgs ra = {{c0, c1, c2}, {pg1, eg1, dg1}, {r0, r1, r2}};
      rms_kernel<<<dim3(Mv, 3), 128, 0, stream>>>(ra); }
    // conv2
    { GArgs<3> a = {{r0, r1, r2}, {wt[3], wt[5], wt[1]}, {pb2, eb2, db2}, {c0, c1, c2}};
      gemm_bf16_kernel<3, 0, 3><<<g3, 256, 0, stream>>>(a, nullptr, nullptr, nullptr,
                                                        nullptr, nullptr, zp); }
    // fused rms2 + linear head -> preds at PIT|ENG|DUR (contiguous, z-ordered)
    { RlArgs ra = {{c0, c1, c2}, {pg2, eg2, dg2}, {pwl, ewl, dwl}, {pbl, ebl, dbl}};
      rmslin_kernel<<<dim3(Mv / 4, 3), 256, 0, stream>>>(ra, mask, outf + PIT_OFF); }

    // length regulate gather -> out (overwrites all d_out-front scratch)
    regulate_kernel<<<Bv * Tv, 128, 0, stream>>>(xob, tmap, outf + OUT_OFF);
}

// Round 5
// 868.943 us; speedup vs baseline: 1.0135x; 1.0135x over previous
//
#include <hip/hip_runtime.h>

// Problem constants
#define Bv    32
#define Lv    512
#define Hv    512
#define Fv    512
#define Tv    4096
#define Mv    (Bv*Lv)          // 16384 rows
#define NBINSv 256

// d_out layout (floats): out(B,T,H) | pit(B,L) | eng(B,L) | log_dur(B,L) | mel_len(B)
#define OUT_OFF 0
#define PIT_OFF (Bv*(size_t)Tv*Hv)              // 67108864
#define ENG_OFF (PIT_OFF + Mv)
#define DUR_OFF (ENG_OFF + Mv)
#define MEL_OFF (DUR_OFF + Mv)

typedef unsigned short ushort;
typedef __attribute__((ext_vector_type(8))) short   bf16x8;   // 8 bf16 in 4 VGPRs
typedef __attribute__((ext_vector_type(4))) float   f32x4;
typedef __attribute__((ext_vector_type(8))) unsigned short u16x8;

__device__ __forceinline__ float b2f(ushort u) {
    union { float f; unsigned u; } x; x.u = ((unsigned)u) << 16; return x.f;
}
__device__ __forceinline__ ushort f2b(float f) {
    union { float f; unsigned u; } x; x.f = f;
    unsigned r = x.u + 0x7fffu + ((x.u >> 16) & 1u);   // RNE
    return (ushort)(r >> 16);
}

#define GLL16(g, l) __builtin_amdgcn_global_load_lds( \
    (const __attribute__((address_space(1))) void*)(g), \
    (__attribute__((address_space(3))) void*)(l), 16, 0, 0)

// Struct-of-pointers kernel args for z-batched launches
template<int NZ> struct GArgs {
    const ushort* A[NZ];
    const ushort* W[NZ];
    const float*  bias[NZ];
    ushort*       C[NZ];
    int           epi[NZ];   // 0 relu; 1 relu+res; 2 relu+res+pe+ee
};
struct RmsArgs   { const ushort* h[3]; const float* g[3]; ushort* o[3]; };
struct RlArgs    { const ushort* h[3]; const float* g[3]; const float* wl[3]; const float* bl[3]; };
struct TransArgs { const float* src[6]; ushort* dst[6]; };
struct ConvArgs  { const float* src[2]; ushort* dst[2]; };

// ---------------------------------------------------------------------------
// bf16 MFMA GEMM, z-batched, double-buffered LDS (ONE barrier per K-iter).
// C[m,n] = epi( sum A*Wt + bias ).  Tile 128x128, BK=32, 4 waves, 4x4 MFMA.
// Operand-swapped: acc[j][i] = mfma(Wfrag[j], Afrag[i], acc) -> lane holds 4
// consecutive n -> vectorized epilogue (8B stores / float4 loads).
// XOR k-chunk swizzle: LDS slot s holds global chunk (s - row/2)&3; reader
// uses slot (q + row/2)&3 -> 2-way-max LDS read conflicts (free, m136).
// NTAPS=3 folds conv taps, zero pad via zero-page redirect.
// ---------------------------------------------------------------------------
template<int NTAPS, int NZ>
__global__ __launch_bounds__(256) void gemm_bf16_kernel(
    GArgs<NZ> ga, const float* __restrict__ res, const float* __restrict__ pe,
    const float* __restrict__ ee, const int* __restrict__ idxp,
    const int* __restrict__ idxe, const ushort* __restrict__ zp)
{
    constexpr int KTOT = NTAPS * 512;
    constexpr int KT   = NTAPS * 16;
    const int z = (NZ > 1) ? blockIdx.z : 0;
    const ushort* __restrict__ A    = ga.A[z];
    const ushort* __restrict__ Bt   = ga.W[z];
    const float*  __restrict__ bias = ga.bias[z];
    ushort*       __restrict__ C    = ga.C[z];
    const int em = ga.epi[z];

    __shared__ ushort As[2][128 * 32];
    __shared__ ushort Bs[2][128 * 32];

    const int tid = threadIdx.x;
    const int n0 = blockIdx.x * 128;
    const int m0 = blockIdx.y * 128;

    const int sar = tid >> 2;                 // staging row 0..63 (+64)
    const int sl  = tid & 3;                  // LDS 16B slot
    const int qg  = ((sl - (sar >> 1)) & 3) << 3;  // source k-chunk (elems)

    const int lane = tid & 63;
    const int w    = tid >> 6;
    const int wm   = (w & 1) * 64;
    const int wn   = (w >> 1) * 64;
    const int lr   = lane & 15;
    const int q    = lane >> 4;
    const int slot = ((q + (lr >> 1)) & 3) << 3;   // fragment read slot (elems)

    // LDS staging destinations per buffer
    ushort* ad[2][2];
    ushort* bd[2][2];
    #pragma unroll
    for (int b = 0; b < 2; ++b) {
        ad[b][0] = &As[b][sar * 32 + sl * 8];
        ad[b][1] = &As[b][(sar + 64) * 32 + sl * 8];
        bd[b][0] = &Bs[b][sar * 32 + sl * 8];
        bd[b][1] = &Bs[b][(sar + 64) * 32 + sl * 8];
    }

    // stage K-iter kt into buffer buf
    auto stage = [&](int kt, int buf) {
        const int tap = (NTAPS == 3) ? (kt >> 4) : 0;
        const int kin = (kt & 15) << 5;
        #pragma unroll
        for (int r = 0; r < 2; ++r) {
            const int row = sar + r * 64;
            const int m   = m0 + row;
            const ushort* asrc;
            if (NTAPS == 3) {
                const int ls = (m & (Lv - 1)) + tap - 1;
                asrc = ((unsigned)ls < (unsigned)Lv)
                     ? A + (size_t)(m + tap - 1) * 512 + kin + qg : zp;
            } else {
                asrc = A + (size_t)m * 512 + kin + qg;
            }
            GLL16(asrc, ad[buf][r]);
            const ushort* bsrc = Bt + (size_t)(n0 + row) * KTOT + tap * 512 + kin + qg;
            GLL16(bsrc, bd[buf][r]);
        }
    };

    f32x4 acc[4][4];   // acc[j][i]: j = n-tile, i = m-tile
    #pragma unroll
    for (int j = 0; j < 4; ++j)
        #pragma unroll
        for (int i = 0; i < 4; ++i) {
            f32x4 zz = {0.f, 0.f, 0.f, 0.f};
            acc[j][i] = zz;
        }

    stage(0, 0);
    for (int kt = 0; kt < KT; ++kt) {
        const int cur = kt & 1;
        __syncthreads();                       // buf[cur] staged; buf[cur^1] free
        if (kt + 1 < KT) stage(kt + 1, cur ^ 1);

        bf16x8 af[4], bfr[4];
        #pragma unroll
        for (int i = 0; i < 4; ++i) {
            af[i]  = *(const bf16x8*)&As[cur][(wm + i * 16 + lr) * 32 + slot];
            bfr[i] = *(const bf16x8*)&Bs[cur][(wn + i * 16 + lr) * 32 + slot];
        }
        #pragma unroll
        for (int j = 0; j < 4; ++j)
            #pragma unroll
            for (int i = 0; i < 4; ++i)
                acc[j][i] = __builtin_amdgcn_mfma_f32_16x16x32_bf16(
                                bfr[j], af[i], acc[j][i], 0, 0, 0);
    }

    // Vectorized epilogue: lane owns m = wm+i*16+lr, n = wn+j*16+q*4 .. +3
    #pragma unroll
    for (int i = 0; i < 4; ++i) {
        const int m = m0 + wm + i * 16 + lr;
        const size_t ro = (size_t)m * 512;
        int ip = 0, ie = 0;
        if (em == 2) { ip = idxp[m]; ie = idxe[m]; }
        #pragma unroll
        for (int j = 0; j < 4; ++j) {
            const int n = n0 + wn + j * 16 + q * 4;
            const f32x4 a = acc[j][i];
            const float4 bi = *(const float4*)(bias + n);
            float v0 = fmaxf(a[0] + bi.x, 0.f);
            float v1 = fmaxf(a[1] + bi.y, 0.f);
            float v2 = fmaxf(a[2] + bi.z, 0.f);
            float v3 = fmaxf(a[3] + bi.w, 0.f);
            if (em >= 1) {
                const float4 r4 = *(const float4*)(res + ro + n);
                v0 += r4.x; v1 += r4.y; v2 += r4.z; v3 += r4.w;
            }
            if (em == 2) {
                const float4 p4 = *(const float4*)(pe + (size_t)ip * 512 + n);
                const float4 e4 = *(const float4*)(ee + (size_t)ie * 512 + n);
                v0 += p4.x + e4.x; v1 += p4.y + e4.y;
                v2 += p4.z + e4.z; v3 += p4.w + e4.w;
            }
            ushort4 o4;
            o4.x = f2b(v0); o4.y = f2b(v1); o4.z = f2b(v2); o4.w = f2b(v3);
            *(ushort4*)(C + ro + n) = o4;
        }
    }
}

// ---------------------------------------------------------------------------
// fp32 -> bf16 convert, batched over {x, emb}
// ---------------------------------------------------------------------------
__global__ __launch_bounds__(256) void convert_kernel(ConvArgs ca)
{
    const float* __restrict__ X  = ca.src[blockIdx.y];
    ushort*      __restrict__ Xb = ca.dst[blockIdx.y];
    const size_t i = (size_t)blockIdx.x * 256 + threadIdx.x;
    const float4 a = ((const float4*)X)[2 * i];
    const float4 b = ((const float4*)X)[2 * i + 1];
    u16x8 o;
    o[0] = f2b(a.x); o[1] = f2b(a.y); o[2] = f2b(a.z); o[3] = f2b(a.w);
    o[4] = f2b(b.x); o[5] = f2b(b.y); o[6] = f2b(b.z); o[7] = f2b(b.w);
    *(u16x8*)(Xb + i * 8) = o;
}

// ---------------------------------------------------------------------------
// Weight transpose+convert, z-batched: W[kk][n] fp32 -> Wt[n][kk] bf16
// ---------------------------------------------------------------------------
__global__ __launch_bounds__(256) void transpose_kernel(TransArgs ta, int Ktot)
{
    const float* __restrict__ W  = ta.src[blockIdx.z];
    ushort*      __restrict__ Wt = ta.dst[blockIdx.z];
    __shared__ float t[32][33];
    const int k0 = blockIdx.x * 32, n0 = blockIdx.y * 32;
    const int r = threadIdx.x >> 5, c = threadIdx.x & 31;
    #pragma unroll
    for (int rr = 0; rr < 4; ++rr)
        t[r + rr * 8][c] = W[(size_t)(k0 + r + rr * 8) * 512 + n0 + c];
    __syncthreads();
    #pragma unroll
    for (int rr = 0; rr < 4; ++rr)
        Wt[(size_t)(n0 + r + rr * 8) * Ktot + k0 + c] = f2b(t[c][r + rr * 8]);
}

// ---------------------------------------------------------------------------
// RMSNorm, z-batched. bf16 in/out, fp32 math.
// ---------------------------------------------------------------------------
__global__ __launch_bounds__(128) void rms_kernel(RmsArgs ra)
{
    const int z = blockIdx.y;
    const int row = blockIdx.x;
    const int tid = threadIdx.x;
    const ushort* __restrict__ h = ra.h[z];
    const ushort4 hv = ((const ushort4*)(h + (size_t)row * 512))[tid];
    const float v0 = b2f(hv.x), v1 = b2f(hv.y), v2 = b2f(hv.z), v3 = b2f(hv.w);
    float ss = v0 * v0 + v1 * v1 + v2 * v2 + v3 * v3;
    #pragma unroll
    for (int off = 32; off; off >>= 1) ss += __shfl_down(ss, off, 64);
    __shared__ float p[2];
    if ((tid & 63) == 0) p[tid >> 6] = ss;
    __syncthreads();
    const float tot = p[0] + p[1];
    const float inv = 1.f / (sqrtf(tot * (1.f / 512.f)) + 1e-8f);
    const float4 gv = ((const float4*)ra.g[z])[tid];
    ushort4 ov;
    ov.x = f2b(gv.x * v0 * inv); ov.y = f2b(gv.y * v1 * inv);
    ov.z = f2b(gv.z * v2 * inv); ov.w = f2b(gv.w * v3 * inv);
    ((ushort4*)(ra.o[z] + (size_t)row * 512))[tid] = ov;
}

// ---------------------------------------------------------------------------
// Fused RMSNorm + linear head, z-batched. pred = mask ? 0 : inv*sum(g*h*wl)+bl
// ---------------------------------------------------------------------------
__global__ __launch_bounds__(256) void rmslin_kernel(
    RlArgs ra, const unsigned char* __restrict__ mask, float* __restrict__ predbase)
{
    const int z = blockIdx.y;
    const int wave = threadIdx.x >> 6, lane = threadIdx.x & 63;
    const int row = blockIdx.x * 4 + wave;
    const ushort* __restrict__ h = ra.h[z];
    const bf16x8 hv = *(const bf16x8*)(h + (size_t)row * 512 + lane * 8);
    const float4 g0 = *(const float4*)(ra.g[z] + lane * 8);
    const float4 g1 = *(const float4*)(ra.g[z] + lane * 8 + 4);
    const float4 w0 = *(const float4*)(ra.wl[z] + lane * 8);
    const float4 w1 = *(const float4*)(ra.wl[z] + lane * 8 + 4);
    float hf[8];
    #pragma unroll
    for (int t = 0; t < 8; ++t) hf[t] = b2f((ushort)hv[t]);
    float ss = 0.f, sgw = 0.f;
    #pragma unroll
    for (int t = 0; t < 8; ++t) ss += hf[t] * hf[t];
    sgw += hf[0]*g0.x*w0.x + hf[1]*g0.y*w0.y + hf[2]*g0.z*w0.z + hf[3]*g0.w*w0.w;
    sgw += hf[4]*g1.x*w1.x + hf[5]*g1.y*w1.y + hf[6]*g1.z*w1.z + hf[7]*g1.w*w1.w;
    #pragma unroll
    for (int off = 32; off; off >>= 1) {
        ss  += __shfl_down(ss,  off, 64);
        sgw += __shfl_down(sgw, off, 64);
    }
    if (lane == 0) {
        const float inv = 1.f / (sqrtf(ss * (1.f / 512.f)) + 1e-8f);
        predbase[(size_t)z * Mv + row] = mask[row] ? 0.f : (sgw * inv + ra.bl[z][0]);
    }
}

// ---------------------------------------------------------------------------
// searchsorted(bins, v, 'left') for pitch & energy targets
// ---------------------------------------------------------------------------
__global__ __launch_bounds__(256) void idx_kernel(
    const float* __restrict__ pt, const float* __restrict__ et,
    const float* __restrict__ pbins, const float* __restrict__ ebins,
    int* __restrict__ idxp, int* __restrict__ idxe)
{
    __shared__ float pb[NBINSv - 1], ebn[NBINSv - 1];
    const int tid = threadIdx.x;
    if (tid < NBINSv - 1) { pb[tid] = pbins[tid]; ebn[tid] = ebins[tid]; }
    __syncthreads();
    const int m = blockIdx.x * 256 + tid;
    const float pv = pt[m], ev = et[m];
    int lo = 0, hi = NBINSv - 1;
    while (lo < hi) { int mid = (lo + hi) >> 1; if (pb[mid] < pv) lo = mid + 1; else hi = mid; }
    idxp[m] = lo;
    lo = 0; hi = NBINSv - 1;
    while (lo < hi) { int mid = (lo + hi) >> 1; if (ebn[mid] < ev) lo = mid + 1; else hi = mid; }
    idxe[m] = lo;
}

// ---------------------------------------------------------------------------
// Fused cumsum + mel_len + regulate source map (one block per batch)
// ---------------------------------------------------------------------------
__global__ __launch_bounds__(512) void cumtmap_kernel(
    const int* __restrict__ dur, float* __restrict__ melout, int* __restrict__ tmap)
{
    __shared__ int s[Lv];
    const int b = blockIdx.x, tid = threadIdx.x;
    s[tid] = dur[b * Lv + tid];
    __syncthreads();
    for (int off = 1; off < Lv; off <<= 1) {
        int t = (tid >= off) ? s[tid - off] : 0;
        __syncthreads();
        s[tid] += t;
        __syncthreads();
    }
    const int mel = s[Lv - 1];
    if (tid == 0) melout[b] = (float)mel;
    #pragma unroll
    for (int rr = 0; rr < Tv / 512; ++rr) {
        const int t = tid + rr * 512;
        int lo = 0, hi = Lv;
        while (lo < hi) { int mid = (lo + hi) >> 1; if (s[mid] <= t) lo = mid + 1; else hi = mid; }
        tmap[b * Tv + t] = (t < mel) ? (b * Lv + min(lo, Lv - 1)) : -1;
    }
}

// ---------------------------------------------------------------------------
// Length regulate gather: out[bt,:] = tmap[bt] >= 0 ? xo[tmap[bt],:] : 0
// ---------------------------------------------------------------------------
__global__ __launch_bounds__(128) void regulate_kernel(
    const ushort* __restrict__ xo, const int* __restrict__ tmap,
    float* __restrict__ out)
{
    const int bt = blockIdx.x;
    const int src = tmap[bt];
    float4 v = make_float4(0.f, 0.f, 0.f, 0.f);
    if (src >= 0) {
        const ushort4 u = ((const ushort4*)(xo + (size_t)src * 512))[threadIdx.x];
        v.x = b2f(u.x); v.y = b2f(u.y); v.z = b2f(u.z); v.w = b2f(u.w);
    }
    ((float4*)(out + (size_t)bt * 512))[threadIdx.x] = v;
}

// ---------------------------------------------------------------------------
extern "C" void kernel_launch(void* const* d_in, const int* in_sizes, int n_in,
                              void* d_out, int out_size, void* d_ws, size_t ws_size,
                              hipStream_t stream)
{
    const float* x    = (const float*)d_in[0];
    const float* emb  = (const float*)d_in[1];
    const unsigned char* mask = (const unsigned char*)d_in[2];
    const int*   durt = (const int*)d_in[3];
    const float* pt   = (const float*)d_in[4];
    const float* et   = (const float*)d_in[5];
    const float* dw1 = (const float*)d_in[7],  *db1 = (const float*)d_in[8],
               * dg1 = (const float*)d_in[9],  *dw2 = (const float*)d_in[10],
               * db2 = (const float*)d_in[11], *dg2 = (const float*)d_in[12],
               * dwl = (const float*)d_in[13], *dbl = (const float*)d_in[14];
    const float* pw1 = (const float*)d_in[15], *pb1 = (const float*)d_in[16],
               * pg1 = (const float*)d_in[17], *pw2 = (const float*)d_in[18],
               * pb2 = (const float*)d_in[19], *pg2 = (const float*)d_in[20],
               * pwl = (const float*)d_in[21], *pbl = (const float*)d_in[22];
    const float* ew1 = (const float*)d_in[23], *eb1 = (const float*)d_in[24],
               * eg1 = (const float*)d_in[25], *ew2 = (const float*)d_in[26],
               * eb2 = (const float*)d_in[27], *eg2 = (const float*)d_in[28],
               * ewl = (const float*)d_in[29], *ebl = (const float*)d_in[30];
    const float* ppw1 = (const float*)d_in[31], *ppb1 = (const float*)d_in[32],
               * ppw2 = (const float*)d_in[33], *ppb2 = (const float*)d_in[34];
    const float* epw1 = (const float*)d_in[35], *epb1 = (const float*)d_in[36],
               * epw2 = (const float*)d_in[37], *epb2 = (const float*)d_in[38];
    const float* spw1 = (const float*)d_in[39], *spb1 = (const float*)d_in[40],
               * spw2 = (const float*)d_in[41], *spb2 = (const float*)d_in[42];
    const float* pbins = (const float*)d_in[43];
    const float* ebins = (const float*)d_in[44];
    const float* pemb  = (const float*)d_in[45];
    const float* eemb  = (const float*)d_in[46];

    float* outf = (float*)d_out;

    // ---- ws scratch (int offsets) ----
    int*    idxp   = (int*)d_ws;                    // 16384
    int*    idxe   = idxp + 16384;                  // 16384
    ushort* zp     = (ushort*)(idxe + 16384);       // 32 ushorts (16B-aligned)
    int*    tmap   = idxe + 16448;                  // 131072
    ushort* xob    = (ushort*)((float*)d_ws + 262144);  // Mv*512 bf16, 1MB offset

    // ---- d_out front scratch (float offsets; regulate overwrites all) ----
    #define OBUF(i) ((ushort*)(outf + (size_t)(i) * 4194304))
    ushort* xb  = OBUF(0);   ushort* eb  = OBUF(1);
    ushort* pA0 = OBUF(2);   ushort* pA1 = OBUF(3);  ushort* pA2 = OBUF(4);
    ushort* xp  = OBUF(5);   ushort* xe  = OBUF(6);
    ushort* c0  = OBUF(7);   ushort* c1  = OBUF(8);  ushort* c2  = OBUF(9);
    ushort* r0  = OBUF(10);  ushort* r1  = OBUF(11); ushort* r2  = OBUF(12);
    ushort* wt[12];
    {
        size_t off = 13ull * 4194304;
        for (int i = 0; i < 6; ++i)  { wt[i] = (ushort*)(outf + off); off += 393216; }  // conv 1536x512
        for (int i = 6; i < 12; ++i) { wt[i] = (ushort*)(outf + off); off += 131072; }  // proj 512x512
    }

    hipMemsetAsync(zp, 0, 64, stream);

    { ConvArgs ca = {{x, emb}, {xb, eb}};
      convert_kernel<<<dim3(4096, 2), 256, 0, stream>>>(ca); }
    { TransArgs ta = {{dw1, dw2, pw1, pw2, ew1, ew2}, {wt[0], wt[1], wt[2], wt[3], wt[4], wt[5]}};
      transpose_kernel<<<dim3(48, 16, 6), 256, 0, stream>>>(ta, 1536); }
    { TransArgs ta = {{ppw1, ppw2, epw1, epw2, spw1, spw2},
                      {wt[6], wt[7], wt[8], wt[9], wt[10], wt[11]}};
      transpose_kernel<<<dim3(16, 16, 6), 256, 0, stream>>>(ta, 512); }

    idx_kernel<<<Mv / 256, 256, 0, stream>>>(pt, et, pbins, ebins, idxp, idxe);
    cumtmap_kernel<<<Bv, Lv, 0, stream>>>(durt, outf + MEL_OFF, tmap);

    const dim3 g3(Fv / 128, Mv / 128, 3);

    // proj1: h = relu(emb @ w1 + b1) for pp/ep/sp
    { GArgs<3> a = {{eb, eb, eb}, {wt[6], wt[8], wt[10]}, {ppb1, epb1, spb1},
                    {pA0, pA1, pA2}, {0, 0, 0}};
      gemm_bf16_kernel<1, 3><<<g3, 256, 0, stream>>>(a, nullptr, nullptr, nullptr,
                                                     nullptr, nullptr, zp); }
    // proj2 (merged): pp/ep -> x + relu(...), sp -> x + pe + ee + relu(...)
    { GArgs<3> a = {{pA0, pA1, pA2}, {wt[7], wt[9], wt[11]}, {ppb2, epb2, spb2},
                    {xp, xe, xob}, {1, 1, 2}};
      gemm_bf16_kernel<1, 3><<<g3, 256, 0, stream>>>(a, x, pemb, eemb, idxp, idxe, zp); }

    // conv1 for {pit, eng, dur}
    { GArgs<3> a = {{xp, xe, xb}, {wt[2], wt[4], wt[0]}, {pb1, eb1, db1},
                    {c0, c1, c2}, {0, 0, 0}};
      gemm_bf16_kernel<3, 3><<<g3, 256, 0, stream>>>(a, nullptr, nullptr, nullptr,
                                                     nullptr, nullptr, zp); }
    { RmsArgs ra = {{c0, c1, c2}, {pg1, eg1, dg1}, {r0, r1, r2}};
      rms_kernel<<<dim3(Mv, 3), 128, 0, stream>>>(ra); }
    // conv2
    { GArgs<3> a = {{r0, r1, r2}, {wt[3], wt[5], wt[1]}, {pb2, eb2, db2},
                    {c0, c1, c2}, {0, 0, 0}};
      gemm_bf16_kernel<3, 3><<<g3, 256, 0, stream>>>(a, nullptr, nullptr, nullptr,
                                                     nullptr, nullptr, zp); }
    // fused rms2 + linear head -> preds at PIT|ENG|DUR (contiguous, z-ordered)
    { RlArgs ra = {{c0, c1, c2}, {pg2, eg2, dg2}, {pwl, ewl, dwl}, {pbl, ebl, dbl}};
      rmslin_kernel<<<dim3(Mv / 4, 3), 256, 0, stream>>>(ra, mask, outf + PIT_OFF); }

    // length regulate gather -> out (overwrites all d_out-front scratch)
    regulate_kernel<<<Bv * Tv, 128, 0, stream>>>(xob, tmap, outf + OUT_OFF);
}